// Round 3
// baseline (297.253 us; speedup 1.0000x reference)
//
#include <hip/hip_runtime.h>
#include <math.h>

#define SEQ   2048
#define DH    64
#define NBH   24
#define NCH   (SEQ / 128)     // 16 chunks of 128 k-cols
// scale * log2(e): softmax in exp2 domain
#define QSCALE 0.18033688011112042f

typedef __attribute__((ext_vector_type(8))) short short8;
typedef __attribute__((ext_vector_type(4))) float f32x4;
typedef __attribute__((ext_vector_type(4))) int   int4v;

#define MFMA(a, b, c) __builtin_amdgcn_mfma_f32_16x16x32_bf16((a), (b), (c), 0, 0, 0)

__device__ __forceinline__ unsigned bf16u(float f) {   // RNE-rounded, result in high 16
    union { float f; unsigned u; } x; x.f = f;
    return x.u + 0x7fffu + ((x.u >> 16) & 1u);
}
__device__ __forceinline__ short bf16rne(float f) { return (short)(bf16u(f) >> 16); }
__device__ __forceinline__ unsigned pack_bf162(float lo, float hi) {
    return (bf16u(lo) >> 16) | (bf16u(hi) & 0xffff0000u);
}

// ---- fused pre-pass: Q(+scale),K fp32->bf16 row-major; V -> V^T bf16 ----
__global__ void cvt_all(const float* __restrict__ q, const float* __restrict__ k,
                        const float* __restrict__ v,
                        short* __restrict__ qb, short* __restrict__ kb,
                        short* __restrict__ vt)
{
    __shared__ short tile[64][72];
    const int t  = threadIdx.x;
    const int bh = blockIdx.x;
    const int s0 = blockIdx.y * 64;
    const size_t base = ((size_t)bh * SEQ + s0) * DH;

    // Q and K: 64x64 tile = 1024 float4 groups, 4 per thread
    #pragma unroll
    for (int i = 0; i < 4; ++i) {
        const int idx = i * 256 + t;
        float4 a = ((const float4*)(q + base))[idx];
        ((int2*)(qb + base))[idx] = make_int2(
            (int)pack_bf162(a.x * QSCALE, a.y * QSCALE),
            (int)pack_bf162(a.z * QSCALE, a.w * QSCALE));
        float4 b = ((const float4*)(k + base))[idx];
        ((int2*)(kb + base))[idx] = make_int2(
            (int)pack_bf162(b.x, b.y), (int)pack_bf162(b.z, b.w));
    }

    // V transpose via LDS tile (verified in round 2)
    {
        const int sl = t >> 2, dg = (t & 3) * 16;
        const float* src = v + base + (size_t)sl * DH + dg;
        short8 r0, r1;
        #pragma unroll
        for (int j = 0; j < 8; ++j) {
            r0[j] = bf16rne(src[j]);
            r1[j] = bf16rne(src[8 + j]);
        }
        *(short8*)(&tile[sl][dg])     = r0;
        *(short8*)(&tile[sl][dg + 8]) = r1;
    }
    __syncthreads();
    {
        const int dl = t >> 2, sg = (t & 3) * 16;
        short8 r0, r1;
        #pragma unroll
        for (int j = 0; j < 8; ++j) {
            r0[j] = tile[sg + j][dl];
            r1[j] = tile[sg + 8 + j][dl];
        }
        short* dst = vt + (size_t)bh * DH * SEQ + (size_t)dl * SEQ + s0 + sg;
        *(short8*)(dst)     = r0;
        *(short8*)(dst + 8) = r1;
    }
}

// ---- main: split-K flash attention, bf16 MFMA, LDS only for final merge ----
// Block = 4 waves over 32 q-rows: wave (qgrp,khalf); khalf 0/1 process chunk
// halves [0,8)/[8,16); merged at the end via LDS (flash combine).
// grid.x = bh so all blocks of one head share an XCD (L2 locality).
__global__ __launch_bounds__(256, 6)
void attn_fwd(const short* __restrict__ qb, const short* __restrict__ kb,
              const short* __restrict__ vt, float* __restrict__ og)
{
    __shared__ float lds_o[2][64][16];
    __shared__ float lds_m[2][16];
    __shared__ float lds_l[2][16];

    const int lane  = threadIdx.x & 63;
    const int wave  = threadIdx.x >> 6;
    const int qgrp  = wave >> 1;
    const int khalf = wave & 1;
    const int quad  = lane >> 4;
    const int l16   = lane & 15;
    const int bh    = blockIdx.x;
    const int q0    = blockIdx.y * 32 + qgrp * 16;

    const short* qrow  = qb + ((size_t)(bh * SEQ + q0 + l16)) * DH + quad * 8;
    const short* kbase = kb + (size_t)bh * SEQ * DH;
    const short* vbase = vt + (size_t)bh * DH * SEQ;

    const short8 bq0 = *(const short8*)(qrow);        // Q^T B-frags d 0..31
    const short8 bq1 = *(const short8*)(qrow + 32);   //             d 32..63

    f32x4 o[4];
    #pragma unroll
    for (int dt = 0; dt < 4; ++dt) o[dt] = (f32x4){0.f, 0.f, 0.f, 0.f};
    float m_i = -INFINITY, l_i = 0.f;

    // perm selector: pick lo16 halves (quad<2) or hi16 halves (quad>=2)
    const unsigned psel   = (quad < 2) ? 0x05040100u : 0x07060302u;
    const int      srcLo  = l16 + ((quad & 1) << 5);   // cross-quad shuffle sources
    const int      srcHi  = srcLo + 16;

    #pragma unroll 1
    for (int kc = khalf * (NCH / 2); kc < (khalf + 1) * (NCH / 2); ++kc) {
        const int k0 = kc * 128;

        // ---- S^T = K @ Q^T : 8 M-tiles, K A-frags straight from global
        f32x4 c[8];
        #pragma unroll
        for (int mt = 0; mt < 8; ++mt) {
            const short* krow = kbase + ((size_t)(k0 + mt * 16 + l16)) * DH + quad * 8;
            short8 ka0 = *(const short8*)(krow);
            short8 ka1 = *(const short8*)(krow + 32);
            f32x4 z = (f32x4){0.f, 0.f, 0.f, 0.f};
            z = MFMA(ka0, bq0, z);
            z = MFMA(ka1, bq1, z);
            c[mt] = z;
        }

        // ---- online softmax (exp2 domain); lane's 32 values share q-row l16
        float vmax = m_i;
        #pragma unroll
        for (int mt = 0; mt < 8; ++mt)
            #pragma unroll
            for (int r = 0; r < 4; ++r) vmax = fmaxf(vmax, c[mt][r]);
        vmax = fmaxf(vmax, __shfl_xor(vmax, 16, 64));
        vmax = fmaxf(vmax, __shfl_xor(vmax, 32, 64));
        const float alpha = __builtin_amdgcn_exp2f(m_i - vmax);
        m_i = vmax;
        float rs = 0.f;
        #pragma unroll
        for (int mt = 0; mt < 8; ++mt)
            #pragma unroll
            for (int r = 0; r < 4; ++r) {
                float p = __builtin_amdgcn_exp2f(c[mt][r] - m_i);
                c[mt][r] = p;
                rs += p;
            }
        rs += __shfl_xor(rs, 16, 64);
        rs += __shfl_xor(rs, 32, 64);
        l_i = l_i * alpha + rs;
        #pragma unroll
        for (int dt = 0; dt < 4; ++dt)
            #pragma unroll
            for (int r = 0; r < 4; ++r) o[dt][r] *= alpha;

        // ---- P^T -> B-frags: pack 2 bf16/word, 8 bpermutes + 4 perms per kch
        #pragma unroll
        for (int kch = 0; kch < 4; ++kch) {
            int sA[4], sB[4];
            #pragma unroll
            for (int r = 0; r < 4; ++r) {
                int w = (int)pack_bf162(c[2 * kch][r], c[2 * kch + 1][r]);
                sA[r] = __shfl(w, srcLo, 64);
                sB[r] = __shfl(w, srcHi, 64);
            }
            int4v pw;
            pw[0] = (int)__builtin_amdgcn_perm((unsigned)sA[1], (unsigned)sA[0], psel);
            pw[1] = (int)__builtin_amdgcn_perm((unsigned)sA[3], (unsigned)sA[2], psel);
            pw[2] = (int)__builtin_amdgcn_perm((unsigned)sB[1], (unsigned)sB[0], psel);
            pw[3] = (int)__builtin_amdgcn_perm((unsigned)sB[3], (unsigned)sB[2], psel);
            short8 pf = __builtin_bit_cast(short8, pw);
            #pragma unroll
            for (int dt = 0; dt < 4; ++dt) {
                const short* vrow = vbase + ((size_t)(dt * 16 + l16)) * SEQ
                                  + k0 + kch * 32 + quad * 8;
                short8 av = *(const short8*)(vrow);
                o[dt] = MFMA(av, pf, o[dt]);
            }
        }
    }

    // ---- cross-wave flash merge (khalf 1 -> LDS, khalf 0 combines+stores)
    if (khalf == 1) {
        #pragma unroll
        for (int dt = 0; dt < 4; ++dt)
            #pragma unroll
            for (int r = 0; r < 4; ++r)
                lds_o[qgrp][lane][dt * 4 + r] = o[dt][r];
        if (quad == 0) { lds_m[qgrp][l16] = m_i; lds_l[qgrp][l16] = l_i; }
    }
    __syncthreads();
    if (khalf == 0) {
        const float m2 = lds_m[qgrp][l16];
        const float l2 = lds_l[qgrp][l16];
        const float m  = fmaxf(m_i, m2);
        const float a1 = __builtin_amdgcn_exp2f(m_i - m);
        const float a2 = __builtin_amdgcn_exp2f(m2 - m);
        const float linv = 1.0f / (l_i * a1 + l2 * a2);
        float* orow = og + ((size_t)(bh * SEQ + q0 + l16)) * DH;
        #pragma unroll
        for (int dt = 0; dt < 4; ++dt) {
            f32x4 st;
            #pragma unroll
            for (int r = 0; r < 4; ++r)
                st[r] = (o[dt][r] * a1 + lds_o[qgrp][lane][dt * 4 + r] * a2) * linv;
            *(f32x4*)(orow + dt * 16 + quad * 4) = st;
        }
    }
}

extern "C" void kernel_launch(void* const* d_in, const int* in_sizes, int n_in,
                              void* d_out, int out_size, void* d_ws, size_t ws_size,
                              hipStream_t stream)
{
    const float* q = (const float*)d_in[0];
    const float* k = (const float*)d_in[1];
    const float* v = (const float*)d_in[2];
    float* o = (float*)d_out;

    const size_t nelem = (size_t)NBH * SEQ * DH;
    short* qb  = (short*)d_ws;
    short* kbp = qb + nelem;
    short* vtp = kbp + nelem;   // 18.9 MB total

    cvt_all<<<dim3(NBH, SEQ / 64), 256, 0, stream>>>(q, k, v, qb, kbp, vtp);
    attn_fwd<<<dim3(NBH, SEQ / 32), 256, 0, stream>>>(qb, kbp, vtp, o);
}

// Round 4
// 257.256 us; speedup vs baseline: 1.1555x; 1.1555x over previous
//
#include <hip/hip_runtime.h>
#include <math.h>

#define SEQ   2048
#define DH    64
#define NBH   24
#define NCH   (SEQ / 128)     // 16 chunks of 128 k-cols
// scale * log2(e): softmax in exp2 domain
#define QSCALE 0.18033688011112042f

typedef __attribute__((ext_vector_type(8))) short short8;
typedef __attribute__((ext_vector_type(4))) float f32x4;
typedef __attribute__((ext_vector_type(4))) int   int4v;

#define MFMA(a, b, c) __builtin_amdgcn_mfma_f32_16x16x32_bf16((a), (b), (c), 0, 0, 0)

__device__ __forceinline__ unsigned bf16u(float f) {   // RNE-rounded, result in high 16
    union { float f; unsigned u; } x; x.f = f;
    return x.u + 0x7fffu + ((x.u >> 16) & 1u);
}
__device__ __forceinline__ unsigned pack_bf162(float lo, float hi) {
    return (bf16u(lo) >> 16) | (bf16u(hi) & 0xffff0000u);
}

// ---- fused pre-pass: Q(+scale),K fp32->bf16 row-major; V -> V^T bf16 ----
// V transpose via fp32 LDS tile, padded stride 65: b128 writes, b32 column
// reads are 2-way-conflict max (free on gfx950).
__global__ __launch_bounds__(256)
void cvt_all(const float* __restrict__ q, const float* __restrict__ k,
             const float* __restrict__ v,
             short* __restrict__ qb, short* __restrict__ kb,
             short* __restrict__ vt)
{
    __shared__ float tile[64][65];
    const int t  = threadIdx.x;
    const int bh = blockIdx.x;
    const int s0 = blockIdx.y * 64;
    const size_t base = ((size_t)bh * SEQ + s0) * DH;

    // Q and K: 64x64 tile = 1024 float4 groups, 4 per thread
    #pragma unroll
    for (int i = 0; i < 4; ++i) {
        const int idx = i * 256 + t;
        float4 a = ((const float4*)(q + base))[idx];
        ((int2*)(qb + base))[idx] = make_int2(
            (int)pack_bf162(a.x * QSCALE, a.y * QSCALE),
            (int)pack_bf162(a.z * QSCALE, a.w * QSCALE));
        float4 b = ((const float4*)(k + base))[idx];
        ((int2*)(kb + base))[idx] = make_int2(
            (int)pack_bf162(b.x, b.y), (int)pack_bf162(b.z, b.w));
    }

    // V rows -> fp32 LDS tile
    {
        const int sl = t >> 2, cg = (t & 3) * 16;
        const float* src = v + base + (size_t)sl * DH + cg;
        #pragma unroll
        for (int i = 0; i < 4; ++i)
            *(float4*)(&tile[sl][cg + 4 * i]) = ((const float4*)src)[i];
    }
    __syncthreads();
    // columns -> bf16 V^T rows (coalesced 32-B stores)
    {
        const int dl = t >> 2, sg = (t & 3) * 16;
        float f[16];
        #pragma unroll
        for (int j = 0; j < 16; ++j) f[j] = tile[sg + j][dl];
        short8 r0, r1;
        #pragma unroll
        for (int j = 0; j < 4; ++j) {
            ((int*)&r0)[j] = (int)pack_bf162(f[2 * j],     f[2 * j + 1]);
            ((int*)&r1)[j] = (int)pack_bf162(f[8 + 2 * j], f[9 + 2 * j]);
        }
        short* dst = vt + (size_t)bh * DH * SEQ + (size_t)dl * SEQ + s0 + sg;
        *(short8*)(dst)     = r0;
        *(short8*)(dst + 8) = r1;
    }
}

// ---- main: split-K flash attention, bf16 MFMA, LDS only for final merge ----
// Block = 4 waves over 32 q-rows: wave (qgrp,khalf); khalf 0/1 process chunk
// halves [0,8)/[8,16); merged at the end via LDS (flash combine).
// grid.x = bh: all 64 blocks of a head land on XCD bh%8 (24%8==0) -> K,V of
// 3 heads (1.5 MB bf16) resident per 4 MB XCD L2.
// launch_bounds(256,4): cap 128 regs. (256,6) spilled (R3: WRITE_SIZE 245 MB).
__global__ __launch_bounds__(256, 4)
void attn_fwd(const short* __restrict__ qb, const short* __restrict__ kb,
              const short* __restrict__ vt, float* __restrict__ og)
{
    __shared__ float lds_o[2][64][16];
    __shared__ float lds_m[2][16];
    __shared__ float lds_l[2][16];

    const int lane  = threadIdx.x & 63;
    const int wave  = threadIdx.x >> 6;
    const int qgrp  = wave >> 1;
    const int khalf = wave & 1;
    const int quad  = lane >> 4;
    const int l16   = lane & 15;
    const int bh    = blockIdx.x;
    const int q0    = blockIdx.y * 32 + qgrp * 16;

    const short* qrow  = qb + ((size_t)(bh * SEQ + q0 + l16)) * DH + quad * 8;
    const short* kbase = kb + (size_t)bh * SEQ * DH;
    const short* vbase = vt + (size_t)bh * DH * SEQ;

    const short8 bq0 = *(const short8*)(qrow);        // Q^T B-frags d 0..31
    const short8 bq1 = *(const short8*)(qrow + 32);   //             d 32..63

    f32x4 o[4];
    #pragma unroll
    for (int dt = 0; dt < 4; ++dt) o[dt] = (f32x4){0.f, 0.f, 0.f, 0.f};
    float m_i = -INFINITY, l_i = 0.f;

    // perm selector: pick lo16 halves (quad<2) or hi16 halves (quad>=2)
    const unsigned psel  = (quad < 2) ? 0x05040100u : 0x07060302u;
    const int      srcLo = l16 + ((quad & 1) << 5);
    const int      srcHi = srcLo + 16;

    #pragma unroll 1
    for (int kc = khalf * (NCH / 2); kc < (khalf + 1) * (NCH / 2); ++kc) {
        const int k0 = kc * 128;

        // ---- S^T = K @ Q^T : 8 M-tiles, K A-frags straight from global
        f32x4 c[8];
        #pragma unroll
        for (int mt = 0; mt < 8; ++mt) {
            const short* krow = kbase + ((size_t)(k0 + mt * 16 + l16)) * DH + quad * 8;
            short8 ka0 = *(const short8*)(krow);
            short8 ka1 = *(const short8*)(krow + 32);
            f32x4 z = (f32x4){0.f, 0.f, 0.f, 0.f};
            z = MFMA(ka0, bq0, z);
            z = MFMA(ka1, bq1, z);
            c[mt] = z;
        }

        // ---- online softmax (exp2 domain); lane's 32 values share q-row l16
        float vmax = m_i;
        #pragma unroll
        for (int mt = 0; mt < 8; ++mt)
            #pragma unroll
            for (int r = 0; r < 4; ++r) vmax = fmaxf(vmax, c[mt][r]);
        vmax = fmaxf(vmax, __shfl_xor(vmax, 16, 64));
        vmax = fmaxf(vmax, __shfl_xor(vmax, 32, 64));
        const float alpha = __builtin_amdgcn_exp2f(m_i - vmax);
        m_i = vmax;
        float rs = 0.f;
        #pragma unroll
        for (int mt = 0; mt < 8; ++mt)
            #pragma unroll
            for (int r = 0; r < 4; ++r) {
                float p = __builtin_amdgcn_exp2f(c[mt][r] - m_i);
                c[mt][r] = p;
                rs += p;
            }
        rs += __shfl_xor(rs, 16, 64);
        rs += __shfl_xor(rs, 32, 64);
        l_i = l_i * alpha + rs;
        #pragma unroll
        for (int dt = 0; dt < 4; ++dt)
            #pragma unroll
            for (int r = 0; r < 4; ++r) o[dt][r] *= alpha;

        // ---- P^T -> B-frags: pack 2 bf16/word, 8 bpermutes + 4 perms per kch
        #pragma unroll
        for (int kch = 0; kch < 4; ++kch) {
            int sA[4], sB[4];
            #pragma unroll
            for (int r = 0; r < 4; ++r) {
                int w = (int)pack_bf162(c[2 * kch][r], c[2 * kch + 1][r]);
                sA[r] = __shfl(w, srcLo, 64);
                sB[r] = __shfl(w, srcHi, 64);
            }
            int4v pw;
            pw[0] = (int)__builtin_amdgcn_perm((unsigned)sA[1], (unsigned)sA[0], psel);
            pw[1] = (int)__builtin_amdgcn_perm((unsigned)sA[3], (unsigned)sA[2], psel);
            pw[2] = (int)__builtin_amdgcn_perm((unsigned)sB[1], (unsigned)sB[0], psel);
            pw[3] = (int)__builtin_amdgcn_perm((unsigned)sB[3], (unsigned)sB[2], psel);
            short8 pf = __builtin_bit_cast(short8, pw);
            #pragma unroll
            for (int dt = 0; dt < 4; ++dt) {
                const short* vrow = vbase + ((size_t)(dt * 16 + l16)) * SEQ
                                  + k0 + kch * 32 + quad * 8;
                short8 av = *(const short8*)(vrow);
                o[dt] = MFMA(av, pf, o[dt]);
            }
        }
    }

    // ---- cross-wave flash merge (khalf 1 -> LDS, khalf 0 combines+stores)
    if (khalf == 1) {
        #pragma unroll
        for (int dt = 0; dt < 4; ++dt)
            #pragma unroll
            for (int r = 0; r < 4; ++r)
                lds_o[qgrp][lane][dt * 4 + r] = o[dt][r];
        if (quad == 0) { lds_m[qgrp][l16] = m_i; lds_l[qgrp][l16] = l_i; }
    }
    __syncthreads();
    if (khalf == 0) {
        const float m2 = lds_m[qgrp][l16];
        const float l2 = lds_l[qgrp][l16];
        const float m  = fmaxf(m_i, m2);
        const float a1 = __builtin_amdgcn_exp2f(m_i - m);
        const float a2 = __builtin_amdgcn_exp2f(m2 - m);
        const float linv = 1.0f / (l_i * a1 + l2 * a2);
        float* orow = og + ((size_t)(bh * SEQ + q0 + l16)) * DH;
        #pragma unroll
        for (int dt = 0; dt < 4; ++dt) {
            f32x4 st;
            #pragma unroll
            for (int r = 0; r < 4; ++r)
                st[r] = (o[dt][r] * a1 + lds_o[qgrp][lane][dt * 4 + r] * a2) * linv;
            *(f32x4*)(orow + dt * 16 + quad * 4) = st;
        }
    }
}

extern "C" void kernel_launch(void* const* d_in, const int* in_sizes, int n_in,
                              void* d_out, int out_size, void* d_ws, size_t ws_size,
                              hipStream_t stream)
{
    const float* q = (const float*)d_in[0];
    const float* k = (const float*)d_in[1];
    const float* v = (const float*)d_in[2];
    float* o = (float*)d_out;

    const size_t nelem = (size_t)NBH * SEQ * DH;
    short* qb  = (short*)d_ws;
    short* kbp = qb + nelem;
    short* vtp = kbp + nelem;   // 18.9 MB total

    cvt_all<<<dim3(NBH, SEQ / 64), 256, 0, stream>>>(q, k, v, qb, kbp, vtp);
    attn_fwd<<<dim3(NBH, SEQ / 32), 256, 0, stream>>>(qb, kbp, vtp, o);
}